// Round 3
// baseline (307.415 us; speedup 1.0000x reference)
//
#include <hip/hip_runtime.h>
#include <hip/hip_bf16.h>

#define N_NODES 100000
#define N_EDGES 1600000
#define IN_CH 256
#define OUT_CH 128

#define BSZ 512            // nodes per bucket (power of 2)
#define NBUCK 196          // ceil(N_NODES / BSZ)
#define BCAP 9216          // bucket capacity: mean 8192, sd ~90 -> 11+ sigma headroom
#define CSC 8192           // edges per block, scatter

#define GEMM_ROWS 32       // rows per block

typedef __attribute__((ext_vector_type(8))) short short8;
typedef __attribute__((ext_vector_type(4))) float floatx4;
typedef __attribute__((ext_vector_type(2))) float float2v;

union bfu { __hip_bfloat16 b; unsigned short u; };

__device__ inline unsigned short f2bf(float v) {
    bfu cv; cv.b = __float2bfloat16(v); return cv.u;
}
__device__ inline float bf2f(unsigned short u) {
    bfu cv; cv.u = u; return __bfloat162float(cv.b);
}

// unpack a packed bf16 pair and accumulate both channels with one v_pk_add_f32
__device__ inline void pkacc(float2v& acc, unsigned g) {
    float2v v;
    v.x = __uint_as_float(g << 16);
    v.y = __uint_as_float(g & 0xffff0000u);
    asm("v_pk_add_f32 %0, %1, %2" : "=v"(acc) : "v"(v), "v"(acc));
}

// ---------- single-pass bucket scatter (capacity-strided buckets) ----------
__global__ __launch_bounds__(256) void pa_scatter(const int* __restrict__ rows,
                                                  const int* __restrict__ cols,
                                                  int* __restrict__ bcursor,
                                                  unsigned* __restrict__ ebuf) {
    __shared__ int lcnt[NBUCK];
    __shared__ int lbase[NBUCK];
    int t = threadIdx.x;
    if (t < NBUCK) lcnt[t] = 0;
    __syncthreads();
    int s0 = blockIdx.x * CSC;
    int e1 = min(N_EDGES, s0 + CSC);
    for (int i = s0 + t; i < e1; i += 256) atomicAdd(&lcnt[cols[i] >> 9], 1);
    __syncthreads();
    if (t < NBUCK) {
        int c = lcnt[t];
        lbase[t] = c ? atomicAdd(&bcursor[t], c) : 0;
        lcnt[t] = 0;
    }
    __syncthreads();
    for (int i = s0 + t; i < e1; i += 256) {
        int c = cols[i], r = rows[i];
        int bk = c >> 9;
        int rank = atomicAdd(&lcnt[bk], 1);
        ebuf[bk * BCAP + lbase[bk] + rank] = ((unsigned)(c & (BSZ - 1)) << 17) | (unsigned)r;
    }
}

// ---------- per-bucket fine sort + cnt/base/dinv, all in LDS ----------
// es entries are stored as BYTE offsets into hbs (src * 256).
__global__ __launch_bounds__(256) void pb_build(const unsigned* __restrict__ ebuf,
                                                const int* __restrict__ bcursor,
                                                int* __restrict__ cnt,
                                                int* __restrict__ base,
                                                float* __restrict__ dinv,
                                                int* __restrict__ es) {
    __shared__ int nh[BSZ];
    __shared__ int sc[BSZ];
    __shared__ int lcur[BSZ];
    int t = threadIdx.x;
    int bk = blockIdx.x;
    int bb = bk * BCAP;
    int bc = bcursor[bk];
    nh[t] = 0; nh[t + 256] = 0;
    lcur[t] = 0; lcur[t + 256] = 0;
    __syncthreads();
    for (int i = t; i < bc; i += 256) atomicAdd(&nh[ebuf[bb + i] >> 17], 1);
    __syncthreads();
    sc[t] = nh[t]; sc[t + 256] = nh[t + 256];
    __syncthreads();
    for (int off = 1; off < BSZ; off <<= 1) {
        int v0 = (t >= off) ? sc[t - off] : 0;
        int i1 = t + 256;
        int v1 = (i1 >= off) ? sc[i1 - off] : 0;
        __syncthreads();
        sc[t] += v0; sc[i1] += v1;
        __syncthreads();
    }
#pragma unroll
    for (int q = 0; q < 2; ++q) {
        int dl = t + q * 256;
        int node = bk * BSZ + dl;
        if (node < N_NODES) {
            int c = nh[dl];
            cnt[node] = c;
            base[node] = bb + sc[dl] - c;
            dinv[node] = rsqrtf((float)(c + 1));
        }
    }
    for (int i = t; i < bc; i += 256) {
        unsigned v = ebuf[bb + i];
        int dl = v >> 17;
        int src = (int)(v & 0x1FFFFu);
        int rank = atomicAdd(&lcur[dl], 1);
        es[bb + sc[dl] - nh[dl] + rank] = src << 8;   // byte offset into hbs
    }
}

// ---------- W (fp32, [256,128]) -> MFMA-fragment-packed bf16 hi/lo ----------
__global__ void k_prep_w(const float* __restrict__ W,
                         unsigned short* __restrict__ wb_hi,
                         unsigned short* __restrict__ wb_lo) {
    int t = blockIdx.x * 256 + threadIdx.x;   // 0..32767
    if (t >= IN_CH * OUT_CH) return;
    int j = t & 7;
    int lane = (t >> 3) & 63;
    int s = (t >> 9) & 7;
    int nt = t >> 12;
    int k = s * 32 + (lane >> 4) * 8 + j;
    int n = nt * 16 + (lane & 15);
    float w = W[k * OUT_CH + n];
    unsigned short hi = f2bf(w);
    wb_hi[t] = hi;
    wb_lo[t] = f2bf(w - bf2f(hi));
}

// ---------- h = x @ W  (fp32 in via split-bf16 MFMA) ----------
__global__ __launch_bounds__(512) void k_gemm(const float* __restrict__ x,
                                              const unsigned short* __restrict__ wb_hi,
                                              const unsigned short* __restrict__ wb_lo,
                                              const float* __restrict__ dinv,
                                              unsigned short* __restrict__ hbs) {
    __shared__ short8 xbh[1024];   // 16 KiB
    __shared__ short8 xbl[1024];   // 16 KiB
    int t = threadIdx.x;
    int wv = t >> 6;        // 0..7 = n-tile
    int lane = t & 63;
    int row0 = blockIdx.x * GEMM_ROWS;

    short8 Bh[8], Bl[8];
    const short8* bhp = (const short8*)wb_hi + (size_t)wv * 8 * 64 + lane;
    const short8* blp = (const short8*)wb_lo + (size_t)wv * 8 * 64 + lane;
#pragma unroll
    for (int s = 0; s < 8; ++s) {
        Bh[s] = bhp[s * 64];
        Bl[s] = blp[s * 64];
    }

#pragma unroll
    for (int q = 0; q < 2; ++q) {
        int slot = q * 512 + t;
        int ms = slot >> 9;
        int s  = (slot >> 6) & 7;
        int l  = slot & 63;
        int row = row0 + ms * 16 + (l & 15);
        int col = s * 32 + (l >> 4) * 8;
        const float4* xp = (const float4*)(x + (size_t)row * IN_CH + col);
        float4 v0 = xp[0];
        float4 v1 = xp[1];
        float xv[8] = {v0.x, v0.y, v0.z, v0.w, v1.x, v1.y, v1.z, v1.w};
        short8 hh, ll;
#pragma unroll
        for (int j = 0; j < 8; ++j) {
            unsigned short hi = f2bf(xv[j]);
            hh[j] = (short)hi;
            ll[j] = (short)f2bf(xv[j] - bf2f(hi));
        }
        xbh[slot] = hh;
        xbl[slot] = ll;
    }
    __syncthreads();

    int r15 = lane & 15;
    int quad = lane >> 4;

    floatx4 acc[2];
#pragma unroll
    for (int ms = 0; ms < 2; ++ms) {
        acc[ms] = (floatx4){0.f, 0.f, 0.f, 0.f};
#pragma unroll
        for (int s = 0; s < 8; ++s) {
            short8 ah = xbh[(ms * 8 + s) * 64 + lane];
            short8 al = xbl[(ms * 8 + s) * 64 + lane];
            acc[ms] = __builtin_amdgcn_mfma_f32_16x16x32_bf16(ah, Bh[s], acc[ms], 0, 0, 0);
            acc[ms] = __builtin_amdgcn_mfma_f32_16x16x32_bf16(ah, Bl[s], acc[ms], 0, 0, 0);
            acc[ms] = __builtin_amdgcn_mfma_f32_16x16x32_bf16(al, Bh[s], acc[ms], 0, 0, 0);
        }
    }

#pragma unroll
    for (int ms = 0; ms < 2; ++ms)
#pragma unroll
        for (int r = 0; r < 4; ++r) {
            int row = row0 + ms * 16 + quad * 4 + r;
            size_t idx = (size_t)row * OUT_CH + wv * 16 + r15;
            hbs[idx] = f2bf(acc[ms][r] * dinv[row]);
        }
}

// ---------- fused gather-aggregate + minmax scale + L2 normalize ----------
// 4 nodes per wave, 16 lanes per node, dwordx4 gathers: one load instruction
// retires FOUR edges (one 256 B row per 16-lane group).  Row offsets are
// broadcast per-group via ds_bpermute from a coalesced es preload.  Padding
// edges read a zero row appended to hbs (numerically exact).
__global__ __launch_bounds__(256) void k_agg_fin(const unsigned short* __restrict__ hbs,
                                                 const float* __restrict__ dinv,
                                                 const int* __restrict__ es,
                                                 const int* __restrict__ base,
                                                 const int* __restrict__ cnt,
                                                 const float* __restrict__ b,
                                                 float* __restrict__ out) {
    int t = threadIdx.x;
    int lane = t & 63;
    int ll = lane & 15;           // lane within node group
    int node = blockIdx.x * 16 + (t >> 4);   // 4 waves x 4 groups, N divisible by 16

    const char* hb = (const char*)hbs;
    int lane_byte = ll << 4;
    int bidx = (lane & 48) << 2;  // bpermute byte index of group's lane 0

    float dn = dinv[node];
    int d  = cnt[node];
    int st = base[node];

    // bias for this lane's 8 channels
    float4 bv0 = ((const float4*)b)[ll * 2];
    float4 bv1 = ((const float4*)b)[ll * 2 + 1];

    // self row (pre-scaled by dinv[node])
    uint4 gs = *(const uint4*)(hb + ((size_t)node << 8) + lane_byte);
    float2v acc[4];
    acc[0].x = __uint_as_float(gs.x << 16); acc[0].y = __uint_as_float(gs.x & 0xffff0000u);
    acc[1].x = __uint_as_float(gs.y << 16); acc[1].y = __uint_as_float(gs.y & 0xffff0000u);
    acc[2].x = __uint_as_float(gs.z << 16); acc[2].y = __uint_as_float(gs.z & 0xffff0000u);
    acc[3].x = __uint_as_float(gs.w << 16); acc[3].y = __uint_as_float(gs.w & 0xffff0000u);

    // wave-uniform iteration count: max degree over the 4 groups
    int dm = d;
    dm = max(dm, __shfl_xor(dm, 16, 64));
    dm = max(dm, __shfl_xor(dm, 32, 64));
    int iters = __builtin_amdgcn_readfirstlane((dm + 15) >> 4);

    const int zoff = N_NODES << 8;   // zero row byte offset

    for (int it = 0; it < iters; ++it) {
        int jb = it << 4;
        int off = zoff;
        if (jb + ll < d) off = es[st + jb + ll];   // 16 offsets per group, coalesced

        uint4 ga[4], gb[4];
#pragma unroll
        for (int k = 0; k < 4; ++k) {
            int ro = __builtin_amdgcn_ds_bpermute(bidx + (k << 2), off);
            ga[k] = *(const uint4*)(hb + (unsigned)(ro + lane_byte));
        }
#pragma unroll
        for (int k = 0; k < 4; ++k) {
            int ro = __builtin_amdgcn_ds_bpermute(bidx + ((4 + k) << 2), off);
            gb[k] = *(const uint4*)(hb + (unsigned)(ro + lane_byte));
        }
#pragma unroll
        for (int k = 0; k < 4; ++k) {
            pkacc(acc[0], ga[k].x); pkacc(acc[1], ga[k].y);
            pkacc(acc[2], ga[k].z); pkacc(acc[3], ga[k].w);
        }
#pragma unroll
        for (int k = 0; k < 4; ++k) {
            int ro = __builtin_amdgcn_ds_bpermute(bidx + ((8 + k) << 2), off);
            ga[k] = *(const uint4*)(hb + (unsigned)(ro + lane_byte));
        }
#pragma unroll
        for (int k = 0; k < 4; ++k) {
            pkacc(acc[0], gb[k].x); pkacc(acc[1], gb[k].y);
            pkacc(acc[2], gb[k].z); pkacc(acc[3], gb[k].w);
        }
#pragma unroll
        for (int k = 0; k < 4; ++k) {
            int ro = __builtin_amdgcn_ds_bpermute(bidx + ((12 + k) << 2), off);
            gb[k] = *(const uint4*)(hb + (unsigned)(ro + lane_byte));
        }
#pragma unroll
        for (int k = 0; k < 4; ++k) {
            pkacc(acc[0], ga[k].x); pkacc(acc[1], ga[k].y);
            pkacc(acc[2], ga[k].z); pkacc(acc[3], ga[k].w);
        }
#pragma unroll
        for (int k = 0; k < 4; ++k) {
            pkacc(acc[0], gb[k].x); pkacc(acc[1], gb[k].y);
            pkacc(acc[2], gb[k].z); pkacc(acc[3], gb[k].w);
        }
    }

    float v[8];
    v[0] = dn * acc[0].x + bv0.x;  v[1] = dn * acc[0].y + bv0.y;
    v[2] = dn * acc[1].x + bv0.z;  v[3] = dn * acc[1].y + bv0.w;
    v[4] = dn * acc[2].x + bv1.x;  v[5] = dn * acc[2].y + bv1.y;
    v[6] = dn * acc[3].x + bv1.z;  v[7] = dn * acc[3].y + bv1.w;

    // min-max over 8 local + 16-lane group
    float lmin = v[0], lmax = v[0];
#pragma unroll
    for (int i = 1; i < 8; ++i) { lmin = fminf(lmin, v[i]); lmax = fmaxf(lmax, v[i]); }
#pragma unroll
    for (int m = 8; m; m >>= 1) {
        lmin = fminf(lmin, __shfl_xor(lmin, m, 64));
        lmax = fmaxf(lmax, __shfl_xor(lmax, m, 64));
    }
    float scale = 1.0f / (lmax - lmin);
    float z[8];
    float ss = 0.f;
#pragma unroll
    for (int i = 0; i < 8; ++i) { z[i] = (v[i] - lmin) * scale; ss += z[i] * z[i]; }
#pragma unroll
    for (int m = 8; m; m >>= 1) ss += __shfl_xor(ss, m, 64);
    float inv = 1.0f / fmaxf(sqrtf(ss), 1e-12f);

    float4 o0 = {z[0] * inv, z[1] * inv, z[2] * inv, z[3] * inv};
    float4 o1 = {z[4] * inv, z[5] * inv, z[6] * inv, z[7] * inv};
    float4* op = (float4*)(out + (size_t)node * OUT_CH);
    op[ll * 2] = o0;
    op[ll * 2 + 1] = o1;
}

extern "C" void kernel_launch(void* const* d_in, const int* in_sizes, int n_in,
                              void* d_out, int out_size, void* d_ws, size_t ws_size,
                              hipStream_t stream) {
    const float* x = (const float*)d_in[0];        // fp32 [N, 256]
    const int* ei = (const int*)d_in[1];           // int32 [2, E]
    const float* W = (const float*)d_in[2];        // fp32 [256, 128]
    const float* b = (const float*)d_in[3];        // fp32 [128]
    float* out = (float*)d_out;                    // fp32 [N, 128]

    char* ws = (char*)d_ws;
    size_t o = 0;
    auto alloc = [&](size_t bytes) { void* p = ws + o; o = (o + bytes + 255) & ~(size_t)255; return p; };
    float* dinv    = (float*)alloc((size_t)N_NODES * 4);
    int*   cnt     = (int*)  alloc((size_t)N_NODES * 4);
    int*   base    = (int*)  alloc((size_t)N_NODES * 4);
    int*   bcursor = (int*)  alloc(NBUCK * 4);
    unsigned short* wb_hi = (unsigned short*)alloc((size_t)IN_CH * OUT_CH * 2);
    unsigned short* wb_lo = (unsigned short*)alloc((size_t)IN_CH * OUT_CH * 2);
    unsigned short* hbs = (unsigned short*)alloc((size_t)(N_NODES + 1) * OUT_CH * 2);  // +1 zero row
    unsigned* ebuf = (unsigned*)alloc((size_t)NBUCK * BCAP * 4);
    int*   es      = (int*)  alloc((size_t)NBUCK * BCAP * 4);

    const int* rows = ei;
    const int* cols = ei + N_EDGES;

    // CSR build: single-pass capacity-strided bucket scatter + per-bucket sort
    hipMemsetAsync(bcursor, 0, NBUCK * sizeof(int), stream);
    hipMemsetAsync(hbs + (size_t)N_NODES * OUT_CH, 0, OUT_CH * 2, stream);  // zero row
    pa_scatter<<<(N_EDGES + CSC - 1) / CSC, 256, 0, stream>>>(rows, cols, bcursor, ebuf);
    pb_build<<<NBUCK, 256, 0, stream>>>(ebuf, bcursor, cnt, base, dinv, es);

    // GEMM
    k_prep_w<<<(IN_CH * OUT_CH + 255) / 256, 256, 0, stream>>>(W, wb_hi, wb_lo);
    k_gemm<<<N_NODES / GEMM_ROWS, 512, 0, stream>>>(x, wb_hi, wb_lo, dinv, hbs);

    // fused aggregate + scale + normalize
    k_agg_fin<<<N_NODES / 16, 256, 0, stream>>>(hbs, dinv, es, base, cnt, b, out);
}

// Round 4
// 284.192 us; speedup vs baseline: 1.0817x; 1.0817x over previous
//
#include <hip/hip_runtime.h>
#include <hip/hip_bf16.h>

#define N_NODES 100000
#define N_EDGES 1600000
#define IN_CH 256
#define OUT_CH 128

#define BSZ 256            // nodes per bucket (power of 2)
#define NBUCK 391          // ceil(N_NODES / BSZ)
#define BCAP 4736          // bucket capacity: mean 4096, sd ~64 -> 10 sigma headroom
#define CSC 4096           // edges per block, scatter

#define GEMM_ROWS 32       // rows per block

typedef __attribute__((ext_vector_type(8))) short short8;
typedef __attribute__((ext_vector_type(4))) float floatx4;
typedef __attribute__((ext_vector_type(2))) float float2v;

union bfu { __hip_bfloat16 b; unsigned short u; };

__device__ inline unsigned short f2bf(float v) {
    bfu cv; cv.b = __float2bfloat16(v); return cv.u;
}
__device__ inline float bf2f(unsigned short u) {
    bfu cv; cv.u = u; return __bfloat162float(cv.b);
}

// unpack a packed bf16 pair and accumulate both channels with one v_pk_add_f32
__device__ inline void pkacc(float2v& acc, unsigned g) {
    float2v v;
    v.x = __uint_as_float(g << 16);
    v.y = __uint_as_float(g & 0xffff0000u);
    asm("v_pk_add_f32 %0, %1, %2" : "=v"(acc) : "v"(v), "v"(acc));
}

// ---------- W prep + workspace zeroing (folds two memsets) ----------
// Stream-ordered before pa_scatter, so bcursor/zero-row are ready in time.
__global__ void k_prep_w(const float* __restrict__ W,
                         unsigned short* __restrict__ wb_hi,
                         unsigned short* __restrict__ wb_lo,
                         int* __restrict__ bcursor,
                         unsigned* __restrict__ zrow) {
    int tid = threadIdx.x;
    if (blockIdx.x == 0) {
        if (tid < NBUCK) bcursor[tid] = 0;
        if (tid + 256 < NBUCK) bcursor[tid + 256] = 0;
    }
    if (blockIdx.x == 1 && tid < 64) zrow[tid] = 0;   // 256 B zero row

    int t = blockIdx.x * 256 + tid;   // 0..32767
    if (t >= IN_CH * OUT_CH) return;
    int j = t & 7;
    int lane = (t >> 3) & 63;
    int s = (t >> 9) & 7;
    int nt = t >> 12;
    int k = s * 32 + (lane >> 4) * 8 + j;
    int n = nt * 16 + (lane & 15);
    float w = W[k * OUT_CH + n];
    unsigned short hi = f2bf(w);
    wb_hi[t] = hi;
    wb_lo[t] = f2bf(w - bf2f(hi));
}

// ---------- single-pass bucket scatter (capacity-strided buckets) ----------
// bucket = dst >> 8.  512 threads, 391 blocks -> ~12 waves/CU.
__global__ __launch_bounds__(512) void pa_scatter(const int* __restrict__ rows,
                                                  const int* __restrict__ cols,
                                                  int* __restrict__ bcursor,
                                                  unsigned* __restrict__ ebuf) {
    __shared__ int lcnt[NBUCK];
    __shared__ int lbase[NBUCK];
    int t = threadIdx.x;
    if (t < NBUCK) lcnt[t] = 0;
    __syncthreads();
    int s0 = blockIdx.x * CSC;
    int e1 = min(N_EDGES, s0 + CSC);
    for (int i = s0 + t; i < e1; i += 512) atomicAdd(&lcnt[cols[i] >> 8], 1);
    __syncthreads();
    if (t < NBUCK) {
        int c = lcnt[t];
        lbase[t] = c ? atomicAdd(&bcursor[t], c) : 0;
        lcnt[t] = 0;
    }
    __syncthreads();
    for (int i = s0 + t; i < e1; i += 512) {
        int c = cols[i], r = rows[i];
        int bk = c >> 8;
        int rank = atomicAdd(&lcnt[bk], 1);
        ebuf[bk * BCAP + lbase[bk] + rank] = ((unsigned)(c & (BSZ - 1)) << 17) | (unsigned)r;
    }
}

// ---------- per-bucket fine sort + cnt/base/dinv, all in LDS ----------
// 512 threads, 391 blocks.  es entries = BYTE offsets into hbs (src * 256).
__global__ __launch_bounds__(512) void pb_build(const unsigned* __restrict__ ebuf,
                                                const int* __restrict__ bcursor,
                                                int* __restrict__ cnt,
                                                int* __restrict__ base,
                                                float* __restrict__ dinv,
                                                int* __restrict__ es) {
    __shared__ int nh[BSZ];
    __shared__ int sc[BSZ];
    __shared__ int lcur[BSZ];
    int t = threadIdx.x;
    int bk = blockIdx.x;
    int bb = bk * BCAP;
    int bc = bcursor[bk];
    if (t < BSZ) { nh[t] = 0; lcur[t] = 0; }
    __syncthreads();
    for (int i = t; i < bc; i += 512) atomicAdd(&nh[ebuf[bb + i] >> 17], 1);
    __syncthreads();
    if (t < BSZ) sc[t] = nh[t];
    __syncthreads();
    for (int off = 1; off < BSZ; off <<= 1) {
        int v = (t < BSZ && t >= off) ? sc[t - off] : 0;
        __syncthreads();
        if (t < BSZ) sc[t] += v;
        __syncthreads();
    }
    if (t < BSZ) {
        int node = bk * BSZ + t;
        if (node < N_NODES) {
            int c = nh[t];
            cnt[node] = c;
            base[node] = bb + sc[t] - c;
            dinv[node] = rsqrtf((float)(c + 1));
        }
    }
    for (int i = t; i < bc; i += 512) {
        unsigned v = ebuf[bb + i];
        int dl = v >> 17;
        int src = (int)(v & 0x1FFFFu);
        int rank = atomicAdd(&lcur[dl], 1);
        es[bb + sc[dl] - nh[dl] + rank] = src << 8;   // byte offset into hbs
    }
}

// ---------- h = x @ W  (fp32 in via split-bf16 MFMA) ----------
// Conversion loads are COALESCED: 32 consecutive lanes read one contiguous
// 1 KB row; the converted chunk is stored to its MFMA fragment slot in a
// padded LDS layout (stride-68 short8 per (ms,s) block, q2 stride 17) that
// keeps both the ds_write and the fragment ds_read_b128 ~conflict-free.
__global__ __launch_bounds__(512) void k_gemm(const float* __restrict__ x,
                                              const unsigned short* __restrict__ wb_hi,
                                              const unsigned short* __restrict__ wb_lo,
                                              const float* __restrict__ dinv,
                                              unsigned short* __restrict__ hbs) {
    __shared__ short8 xbh[2 * 8 * 68];   // 17408 B
    __shared__ short8 xbl[2 * 8 * 68];   // 17408 B
    int t = threadIdx.x;
    int wv = t >> 6;        // 0..7 = n-tile
    int lane = t & 63;
    int row0 = blockIdx.x * GEMM_ROWS;

    // B fragments (L2-resident): issue loads early
    short8 Bh[8], Bl[8];
    const short8* bhp = (const short8*)wb_hi + (size_t)wv * 8 * 64 + lane;
    const short8* blp = (const short8*)wb_lo + (size_t)wv * 8 * 64 + lane;
#pragma unroll
    for (int s = 0; s < 8; ++s) {
        Bh[s] = bhp[s * 64];
        Bl[s] = blp[s * 64];
    }

    // cooperative fp32 -> split-bf16 conversion, 2 chunks (of 8 floats) per thread
#pragma unroll
    for (int q = 0; q < 2; ++q) {
        int c = q * 512 + t;          // 0..1023
        int row = c >> 5;             // 0..31
        int cc  = c & 31;             // col chunk (8 floats)
        const float4* xp = (const float4*)(x + (size_t)(row0 + row) * IN_CH + cc * 8);
        float4 v0 = xp[0];
        float4 v1 = xp[1];
        float xv[8] = {v0.x, v0.y, v0.z, v0.w, v1.x, v1.y, v1.z, v1.w};
        short8 hh, ll;
#pragma unroll
        for (int j = 0; j < 8; ++j) {
            unsigned short hi = f2bf(xv[j]);
            hh[j] = (short)hi;
            ll[j] = (short)f2bf(xv[j] - bf2f(hi));
        }
        int ms = row >> 4, r15 = row & 15, s = cc >> 2, q2 = cc & 3;
        int idx = (ms * 8 + s) * 68 + q2 * 17 + r15;
        xbh[idx] = hh;
        xbl[idx] = ll;
    }
    __syncthreads();

    int r15 = lane & 15;
    int quad = lane >> 4;
    int lidx = quad * 17 + r15;

    floatx4 acc[2];
#pragma unroll
    for (int ms = 0; ms < 2; ++ms) {
        acc[ms] = (floatx4){0.f, 0.f, 0.f, 0.f};
#pragma unroll
        for (int s = 0; s < 8; ++s) {
            short8 ah = xbh[(ms * 8 + s) * 68 + lidx];
            short8 al = xbl[(ms * 8 + s) * 68 + lidx];
            acc[ms] = __builtin_amdgcn_mfma_f32_16x16x32_bf16(ah, Bh[s], acc[ms], 0, 0, 0);
            acc[ms] = __builtin_amdgcn_mfma_f32_16x16x32_bf16(ah, Bl[s], acc[ms], 0, 0, 0);
            acc[ms] = __builtin_amdgcn_mfma_f32_16x16x32_bf16(al, Bh[s], acc[ms], 0, 0, 0);
        }
    }

#pragma unroll
    for (int ms = 0; ms < 2; ++ms)
#pragma unroll
        for (int r = 0; r < 4; ++r) {
            int row = row0 + ms * 16 + quad * 4 + r;
            size_t idx = (size_t)row * OUT_CH + wv * 16 + r15;
            hbs[idx] = f2bf(acc[ms][r] * dinv[row]);
        }
}

// ---------- fused gather-aggregate + minmax scale + L2 normalize ----------
// 4 nodes per wave, 16 lanes per node, dwordx4 gathers (one 256 B row per
// group per instruction).  Fabric-BW-bound at ~3.78 TB/s for this pattern.
__global__ __launch_bounds__(256) void k_agg_fin(const unsigned short* __restrict__ hbs,
                                                 const float* __restrict__ dinv,
                                                 const int* __restrict__ es,
                                                 const int* __restrict__ base,
                                                 const int* __restrict__ cnt,
                                                 const float* __restrict__ b,
                                                 float* __restrict__ out) {
    int t = threadIdx.x;
    int lane = t & 63;
    int ll = lane & 15;           // lane within node group
    int node = blockIdx.x * 16 + (t >> 4);

    const char* hb = (const char*)hbs;
    int lane_byte = ll << 4;
    int bidx = (lane & 48) << 2;  // bpermute byte index of group's lane 0

    float dn = dinv[node];
    int d  = cnt[node];
    int st = base[node];

    float4 bv0 = ((const float4*)b)[ll * 2];
    float4 bv1 = ((const float4*)b)[ll * 2 + 1];

    // self row (pre-scaled by dinv[node])
    uint4 gs = *(const uint4*)(hb + ((size_t)node << 8) + lane_byte);
    float2v acc[4];
    acc[0].x = __uint_as_float(gs.x << 16); acc[0].y = __uint_as_float(gs.x & 0xffff0000u);
    acc[1].x = __uint_as_float(gs.y << 16); acc[1].y = __uint_as_float(gs.y & 0xffff0000u);
    acc[2].x = __uint_as_float(gs.z << 16); acc[2].y = __uint_as_float(gs.z & 0xffff0000u);
    acc[3].x = __uint_as_float(gs.w << 16); acc[3].y = __uint_as_float(gs.w & 0xffff0000u);

    int dm = d;
    dm = max(dm, __shfl_xor(dm, 16, 64));
    dm = max(dm, __shfl_xor(dm, 32, 64));
    int iters = __builtin_amdgcn_readfirstlane((dm + 15) >> 4);

    const int zoff = N_NODES << 8;   // zero row byte offset

    for (int it = 0; it < iters; ++it) {
        int jb = it << 4;
        int off = zoff;
        if (jb + ll < d) off = es[st + jb + ll];

        uint4 ga[4], gb[4];
#pragma unroll
        for (int k = 0; k < 4; ++k) {
            int ro = __builtin_amdgcn_ds_bpermute(bidx + (k << 2), off);
            ga[k] = *(const uint4*)(hb + (unsigned)(ro + lane_byte));
        }
#pragma unroll
        for (int k = 0; k < 4; ++k) {
            int ro = __builtin_amdgcn_ds_bpermute(bidx + ((4 + k) << 2), off);
            gb[k] = *(const uint4*)(hb + (unsigned)(ro + lane_byte));
        }
#pragma unroll
        for (int k = 0; k < 4; ++k) {
            pkacc(acc[0], ga[k].x); pkacc(acc[1], ga[k].y);
            pkacc(acc[2], ga[k].z); pkacc(acc[3], ga[k].w);
        }
#pragma unroll
        for (int k = 0; k < 4; ++k) {
            int ro = __builtin_amdgcn_ds_bpermute(bidx + ((8 + k) << 2), off);
            ga[k] = *(const uint4*)(hb + (unsigned)(ro + lane_byte));
        }
#pragma unroll
        for (int k = 0; k < 4; ++k) {
            pkacc(acc[0], gb[k].x); pkacc(acc[1], gb[k].y);
            pkacc(acc[2], gb[k].z); pkacc(acc[3], gb[k].w);
        }
#pragma unroll
        for (int k = 0; k < 4; ++k) {
            int ro = __builtin_amdgcn_ds_bpermute(bidx + ((12 + k) << 2), off);
            gb[k] = *(const uint4*)(hb + (unsigned)(ro + lane_byte));
        }
#pragma unroll
        for (int k = 0; k < 4; ++k) {
            pkacc(acc[0], ga[k].x); pkacc(acc[1], ga[k].y);
            pkacc(acc[2], ga[k].z); pkacc(acc[3], ga[k].w);
        }
#pragma unroll
        for (int k = 0; k < 4; ++k) {
            pkacc(acc[0], gb[k].x); pkacc(acc[1], gb[k].y);
            pkacc(acc[2], gb[k].z); pkacc(acc[3], gb[k].w);
        }
    }

    float v[8];
    v[0] = dn * acc[0].x + bv0.x;  v[1] = dn * acc[0].y + bv0.y;
    v[2] = dn * acc[1].x + bv0.z;  v[3] = dn * acc[1].y + bv0.w;
    v[4] = dn * acc[2].x + bv1.x;  v[5] = dn * acc[2].y + bv1.y;
    v[6] = dn * acc[3].x + bv1.z;  v[7] = dn * acc[3].y + bv1.w;

    float lmin = v[0], lmax = v[0];
#pragma unroll
    for (int i = 1; i < 8; ++i) { lmin = fminf(lmin, v[i]); lmax = fmaxf(lmax, v[i]); }
#pragma unroll
    for (int m = 8; m; m >>= 1) {
        lmin = fminf(lmin, __shfl_xor(lmin, m, 64));
        lmax = fmaxf(lmax, __shfl_xor(lmax, m, 64));
    }
    float scale = 1.0f / (lmax - lmin);
    float z[8];
    float ss = 0.f;
#pragma unroll
    for (int i = 0; i < 8; ++i) { z[i] = (v[i] - lmin) * scale; ss += z[i] * z[i]; }
#pragma unroll
    for (int m = 8; m; m >>= 1) ss += __shfl_xor(ss, m, 64);
    float inv = 1.0f / fmaxf(sqrtf(ss), 1e-12f);

    float4 o0 = {z[0] * inv, z[1] * inv, z[2] * inv, z[3] * inv};
    float4 o1 = {z[4] * inv, z[5] * inv, z[6] * inv, z[7] * inv};
    float4* op = (float4*)(out + (size_t)node * OUT_CH);
    op[ll * 2] = o0;
    op[ll * 2 + 1] = o1;
}

extern "C" void kernel_launch(void* const* d_in, const int* in_sizes, int n_in,
                              void* d_out, int out_size, void* d_ws, size_t ws_size,
                              hipStream_t stream) {
    const float* x = (const float*)d_in[0];        // fp32 [N, 256]
    const int* ei = (const int*)d_in[1];           // int32 [2, E]
    const float* W = (const float*)d_in[2];        // fp32 [256, 128]
    const float* b = (const float*)d_in[3];        // fp32 [128]
    float* out = (float*)d_out;                    // fp32 [N, 128]

    char* ws = (char*)d_ws;
    size_t o = 0;
    auto alloc = [&](size_t bytes) { void* p = ws + o; o = (o + bytes + 255) & ~(size_t)255; return p; };
    float* dinv    = (float*)alloc((size_t)N_NODES * 4);
    int*   cnt     = (int*)  alloc((size_t)N_NODES * 4);
    int*   base    = (int*)  alloc((size_t)N_NODES * 4);
    int*   bcursor = (int*)  alloc(NBUCK * 4);
    unsigned short* wb_hi = (unsigned short*)alloc((size_t)IN_CH * OUT_CH * 2);
    unsigned short* wb_lo = (unsigned short*)alloc((size_t)IN_CH * OUT_CH * 2);
    unsigned short* hbs = (unsigned short*)alloc((size_t)(N_NODES + 1) * OUT_CH * 2);  // +1 zero row
    unsigned* ebuf = (unsigned*)alloc((size_t)NBUCK * BCAP * 4);
    int*   es      = (int*)  alloc((size_t)NBUCK * BCAP * 4);

    const int* rows = ei;
    const int* cols = ei + N_EDGES;

    // W prep + zero bcursor + zero row (stream-ordered before scatter/agg)
    k_prep_w<<<(IN_CH * OUT_CH + 255) / 256, 256, 0, stream>>>(
        W, wb_hi, wb_lo, bcursor, (unsigned*)(hbs + (size_t)N_NODES * OUT_CH));

    // CSR build: single-pass capacity-strided bucket scatter + per-bucket sort
    pa_scatter<<<(N_EDGES + CSC - 1) / CSC, 512, 0, stream>>>(rows, cols, bcursor, ebuf);
    pb_build<<<NBUCK, 512, 0, stream>>>(ebuf, bcursor, cnt, base, dinv, es);

    // GEMM
    k_gemm<<<N_NODES / GEMM_ROWS, 512, 0, stream>>>(x, wb_hi, wb_lo, dinv, hbs);

    // fused aggregate + scale + normalize
    k_agg_fin<<<N_NODES / 16, 256, 0, stream>>>(hbs, dinv, es, base, cnt, b, out);
}